// Round 2
// baseline (1236.978 us; speedup 1.0000x reference)
//
#include <hip/hip_runtime.h>

#define NN 100000
#define NE 1600000

typedef short v8s __attribute__((ext_vector_type(8)));
typedef float v4f __attribute__((ext_vector_type(4)));
typedef unsigned short v4u16 __attribute__((ext_vector_type(4)));

__device__ __forceinline__ unsigned short f2bf(float f) {
    union { float f; unsigned int u; } v; v.f = f;
    unsigned int r = v.u + 0x7FFFu + ((v.u >> 16) & 1u);  // RNE
    return (unsigned short)(r >> 16);
}

// LDS fragment layout, XOR-swizzled to kill 8-way ds_read_b128 conflicts:
// element (row, k) -> (k>>5)*2048 + row*32 + swz(row, k&31)
// swz swaps 8-element sub-blocks by (row>>1)&3 so consecutive even rows hit
// different bank quads (2-way max aliasing = free on wave64).
__device__ __forceinline__ int swz_p(int row, int p) {
    return (p & 7) | (((((p >> 3) ^ (row >> 1))) & 3) << 3);
}

__device__ __forceinline__ void store_bf4(unsigned short* base, int row, int k, float4 v) {
    v4u16 p;
    p.x = f2bf(v.x); p.y = f2bf(v.y); p.z = f2bf(v.z); p.w = f2bf(v.w);
    *(v4u16*)(base + ((k >> 5) * 2048 + row * 32 + swz_p(row, k & 31))) = p;
}

#define MFMA16(acc, a, b) acc = __builtin_amdgcn_mfma_f32_16x16x32_bf16(a, b, acc, 0, 0, 0)

// ---------------------------------------------------------------------------
// CSR build: count -> scan -> fill gives perm = edge ids sorted by receiver.
// ---------------------------------------------------------------------------
__global__ void count_kernel(const int* __restrict__ rcv, int* cnt) {
    int i = blockIdx.x * 256 + threadIdx.x;
    if (i < NE) atomicAdd(&cnt[rcv[i]], 1);
}

__global__ void scan_kernel(const int* __restrict__ cnt, int* cur) {
    __shared__ int wsum[16];
    __shared__ int carry_s;
    const int tid = threadIdx.x;
    const int lane = tid & 63, w = tid >> 6;
    if (tid == 0) carry_s = 0;
    __syncthreads();
    for (int base = 0; base < NN; base += 1024) {
        int i = base + tid;
        int v = (i < NN) ? cnt[i] : 0;
        int s = v;
#pragma unroll
        for (int off = 1; off < 64; off <<= 1) {
            int t = __shfl_up(s, off, 64);
            if (lane >= off) s += t;
        }
        if (lane == 63) wsum[w] = s;
        __syncthreads();
        int woff = 0;
        for (int j = 0; j < w; ++j) woff += wsum[j];
        int carry = carry_s;
        __syncthreads();
        if (i < NN) cur[i] = carry + woff + s - v;
        if (tid == 1023) carry_s = carry + woff + s;
        __syncthreads();
    }
}

__global__ void fill_kernel(const int* __restrict__ rcv, int* cur, int* perm) {
    int i = blockIdx.x * 256 + threadIdx.x;
    if (i < NE) {
        int p = atomicAdd(&cur[rcv[i]], 1);
        perm[p] = i;
    }
}

// ---------------------------------------------------------------------------
// Edge kernel: per 64-edge tile (receiver-sorted via perm), A = concat(e,
// x[s], x[r]) -> 3-layer bf16 MFMA MLP -> merged atomicAdd into agg.
// LDS: WT1 6*2048 + A 6*2048 = 24576 u16 = 48 KiB -> 3 blocks/CU.
// We2/We3 b-frags live in registers (64 VGPRs, loaded once per block).
// ---------------------------------------------------------------------------
__global__ __launch_bounds__(256, 3) void edge_kernel(
    const float* __restrict__ x, const float* __restrict__ e,
    const int* __restrict__ snd, const int* __restrict__ rcv,
    const float* __restrict__ We1, const float* __restrict__ be1,
    const float* __restrict__ We2, const float* __restrict__ be2,
    const float* __restrict__ We3, const float* __restrict__ be3,
    const int* __restrict__ perm, float* agg, int numTiles)
{
    extern __shared__ unsigned short smem[];
    unsigned short* WT1 = smem;             // 12288 u16 (kb 0..5)
    unsigned short* A   = smem + 12288;     // 12288 u16; H1 in kb0-1, H2 in kb2-3

    const int tid = threadIdx.x;

    // Stage We1 in frag layout (swizzled)
    for (int idx = tid; idx < 192 * 64; idx += 256) {
        int k = idx >> 6, n = idx & 63;
        WT1[(k >> 5) * 2048 + n * 32 + swz_p(n, k & 31)] = f2bf(We1[idx]);
    }

    const int lane = tid & 63;
    const int wv   = tid >> 6;
    const int l15  = lane & 15;
    const int quad = lane >> 4;
    const int astrip = wv * 16;

    // Register-resident b-frags for layers 2 & 3.
    v8s w2f[2][4], w3f[2][4];
#pragma unroll
    for (int kb = 0; kb < 2; ++kb)
#pragma unroll
        for (int nt = 0; nt < 4; ++nt) {
            int n = nt * 16 + l15;
            v8s f2, f3;
#pragma unroll
            for (int j = 0; j < 8; ++j) {
                int k = kb * 32 + quad * 8 + j;
                f2[j] = (short)f2bf(We2[k * 64 + n]);
                f3[j] = (short)f2bf(We3[k * 64 + n]);
            }
            w2f[kb][nt] = f2;
            w3f[kb][nt] = f3;
        }

    float b1v[4], b2v[4], b3v[4];
#pragma unroll
    for (int nt = 0; nt < 4; ++nt) {
        b1v[nt] = be1[nt * 16 + l15];
        b2v[nt] = be2[nt * 16 + l15];
        b3v[nt] = be3[nt * 16 + l15];
    }

    const int amrow = astrip + l15;
    const int aoff  = amrow * 32 + (((quad ^ (amrow >> 1)) & 3) << 3);
    int boff[4];
#pragma unroll
    for (int nt = 0; nt < 4; ++nt) {
        int n = nt * 16 + l15;
        boff[nt] = n * 32 + (((quad ^ (n >> 1)) & 3) << 3);
    }

    __syncthreads();

    for (int tile = blockIdx.x; tile < numTiles; tile += gridDim.x) {
        const int ebase = tile * 64;

        // ---- Gather/stage A: rows = (sorted) edges, k = [e | x[s] | x[r]] ----
#pragma unroll
        for (int t = 0; t < 4; ++t) {
            int idx = tid + t * 256;          // 0..1023
            int row = idx >> 4;
            int k0  = (idx & 15) * 4;
            int eid = perm ? perm[ebase + row] : (ebase + row);
            float4 ve = *(const float4*)(e + (size_t)eid * 64 + k0);
            store_bf4(A, row, k0, ve);
            int s = snd[eid];
            float4 vs = *(const float4*)(x + (size_t)s * 64 + k0);
            store_bf4(A, row, 64 + k0, vs);
            int r = rcv[eid];
            float4 vr = *(const float4*)(x + (size_t)r * 64 + k0);
            store_bf4(A, row, 128 + k0, vr);
        }
        __syncthreads();

        // ---- Layer 1: [64,192]@[192,64], relu -> H1 (kb0-1, own rows) ----
        {
            v4f acc[4];
#pragma unroll
            for (int nt = 0; nt < 4; ++nt) acc[nt] = (v4f){0.f, 0.f, 0.f, 0.f};
#pragma unroll
            for (int kb = 0; kb < 6; ++kb) {
                v8s af = *(const v8s*)(A + kb * 2048 + aoff);
#pragma unroll
                for (int nt = 0; nt < 4; ++nt) {
                    v8s bf = *(const v8s*)(WT1 + kb * 2048 + boff[nt]);
                    MFMA16(acc[nt], af, bf);
                }
            }
#pragma unroll
            for (int nt = 0; nt < 4; ++nt) {
                int kk = nt * 16 + l15;
#pragma unroll
                for (int r = 0; r < 4; ++r) {
                    int m = astrip + quad * 4 + r;
                    float v = acc[nt][r] + b1v[nt];
                    v = v > 0.f ? v : 0.f;
                    A[(kk >> 5) * 2048 + m * 32 + swz_p(m, kk & 31)] = f2bf(v);
                }
            }
        }

        // ---- Layer 2: relu -> H2 (kb2-3) ----
        {
            v4f acc[4];
#pragma unroll
            for (int nt = 0; nt < 4; ++nt) acc[nt] = (v4f){0.f, 0.f, 0.f, 0.f};
#pragma unroll
            for (int kb = 0; kb < 2; ++kb) {
                v8s af = *(const v8s*)(A + kb * 2048 + aoff);
#pragma unroll
                for (int nt = 0; nt < 4; ++nt) MFMA16(acc[nt], af, w2f[kb][nt]);
            }
#pragma unroll
            for (int nt = 0; nt < 4; ++nt) {
                int kk = nt * 16 + l15;
#pragma unroll
                for (int r = 0; r < 4; ++r) {
                    int m = astrip + quad * 4 + r;
                    float v = acc[nt][r] + b2v[nt];
                    v = v > 0.f ? v : 0.f;
                    A[(2 + (kk >> 5)) * 2048 + m * 32 + swz_p(m, kk & 31)] = f2bf(v);
                }
            }
        }

        // ---- Layer 3 -> merged atomic scatter (sorted => few distinct dsts) --
        {
            v4f acc[4];
#pragma unroll
            for (int nt = 0; nt < 4; ++nt) acc[nt] = (v4f){0.f, 0.f, 0.f, 0.f};
#pragma unroll
            for (int kb = 0; kb < 2; ++kb) {
                v8s af = *(const v8s*)(A + (2 + kb) * 2048 + aoff);
#pragma unroll
                for (int nt = 0; nt < 4; ++nt) MFMA16(acc[nt], af, w3f[kb][nt]);
            }
            int dsts[4];
#pragma unroll
            for (int r = 0; r < 4; ++r) {
                int el = astrip + quad * 4 + r;
                int eid = perm ? perm[ebase + el] : (ebase + el);
                dsts[r] = rcv[eid];
            }
            float sum[4];
            int cur = dsts[0];
#pragma unroll
            for (int nt = 0; nt < 4; ++nt) sum[nt] = acc[nt][0] + b3v[nt];
#pragma unroll
            for (int r = 1; r < 4; ++r) {
                if (dsts[r] == cur) {
#pragma unroll
                    for (int nt = 0; nt < 4; ++nt) sum[nt] += acc[nt][r] + b3v[nt];
                } else {
                    float* aggrow = agg + (size_t)cur * 64;
#pragma unroll
                    for (int nt = 0; nt < 4; ++nt)
                        unsafeAtomicAdd(aggrow + nt * 16 + l15, sum[nt]);
                    cur = dsts[r];
#pragma unroll
                    for (int nt = 0; nt < 4; ++nt) sum[nt] = acc[nt][r] + b3v[nt];
                }
            }
            float* aggrow = agg + (size_t)cur * 64;
#pragma unroll
            for (int nt = 0; nt < 4; ++nt)
                unsafeAtomicAdd(aggrow + nt * 16 + l15, sum[nt]);
        }
        __syncthreads();
    }
}

// ---------------------------------------------------------------------------
// Node kernel (persistent): A = concat(x, agg) [64,128] -> MLP -> out (in-place
// over agg rows). LDS: WT1 4*2048 + A 4*2048 = 16384 u16 = 32 KiB.
// ---------------------------------------------------------------------------
__global__ __launch_bounds__(256, 3) void node_kernel(
    const float* __restrict__ x,
    const float* __restrict__ Wn1, const float* __restrict__ bn1,
    const float* __restrict__ Wn2, const float* __restrict__ bn2,
    const float* __restrict__ Wn3, const float* __restrict__ bn3,
    float* aggout, int numTiles)
{
    extern __shared__ unsigned short smem[];
    unsigned short* WT1 = smem;             // 8192 u16 (kb 0..3)
    unsigned short* A   = smem + 8192;      // 8192 u16; H1 kb0-1, H2 kb2-3

    const int tid = threadIdx.x;

    for (int idx = tid; idx < 128 * 64; idx += 256) {
        int k = idx >> 6, n = idx & 63;
        WT1[(k >> 5) * 2048 + n * 32 + swz_p(n, k & 31)] = f2bf(Wn1[idx]);
    }

    const int lane = tid & 63;
    const int wv   = tid >> 6;
    const int l15  = lane & 15;
    const int quad = lane >> 4;
    const int astrip = wv * 16;

    v8s w2f[2][4], w3f[2][4];
#pragma unroll
    for (int kb = 0; kb < 2; ++kb)
#pragma unroll
        for (int nt = 0; nt < 4; ++nt) {
            int n = nt * 16 + l15;
            v8s f2, f3;
#pragma unroll
            for (int j = 0; j < 8; ++j) {
                int k = kb * 32 + quad * 8 + j;
                f2[j] = (short)f2bf(Wn2[k * 64 + n]);
                f3[j] = (short)f2bf(Wn3[k * 64 + n]);
            }
            w2f[kb][nt] = f2;
            w3f[kb][nt] = f3;
        }

    float b1v[4], b2v[4], b3v[4];
#pragma unroll
    for (int nt = 0; nt < 4; ++nt) {
        b1v[nt] = bn1[nt * 16 + l15];
        b2v[nt] = bn2[nt * 16 + l15];
        b3v[nt] = bn3[nt * 16 + l15];
    }

    const int amrow = astrip + l15;
    const int aoff  = amrow * 32 + (((quad ^ (amrow >> 1)) & 3) << 3);
    int boff[4];
#pragma unroll
    for (int nt = 0; nt < 4; ++nt) {
        int n = nt * 16 + l15;
        boff[nt] = n * 32 + (((quad ^ (n >> 1)) & 3) << 3);
    }

    __syncthreads();

    for (int tile = blockIdx.x; tile < numTiles; tile += gridDim.x) {
        const int nbase = tile * 64;

        // ---- Gather: rows = nodes, k = [x | agg] ----
#pragma unroll
        for (int t = 0; t < 4; ++t) {
            int idx = tid + t * 256;
            int row = idx >> 4;
            int k0  = (idx & 15) * 4;
            int node = nbase + row;
            float4 vx = {0.f, 0.f, 0.f, 0.f}, va = {0.f, 0.f, 0.f, 0.f};
            if (node < NN) {
                vx = *(const float4*)(x + (size_t)node * 64 + k0);
                va = *(const float4*)(aggout + (size_t)node * 64 + k0);
            }
            store_bf4(A, row, k0, vx);
            store_bf4(A, row, 64 + k0, va);
        }
        __syncthreads();

        // ---- Layer 1: K=128, relu -> H1 (kb0-1) ----
        {
            v4f acc[4];
#pragma unroll
            for (int nt = 0; nt < 4; ++nt) acc[nt] = (v4f){0.f, 0.f, 0.f, 0.f};
#pragma unroll
            for (int kb = 0; kb < 4; ++kb) {
                v8s af = *(const v8s*)(A + kb * 2048 + aoff);
#pragma unroll
                for (int nt = 0; nt < 4; ++nt) {
                    v8s bf = *(const v8s*)(WT1 + kb * 2048 + boff[nt]);
                    MFMA16(acc[nt], af, bf);
                }
            }
#pragma unroll
            for (int nt = 0; nt < 4; ++nt) {
                int kk = nt * 16 + l15;
#pragma unroll
                for (int r = 0; r < 4; ++r) {
                    int m = astrip + quad * 4 + r;
                    float v = acc[nt][r] + b1v[nt];
                    v = v > 0.f ? v : 0.f;
                    A[(kk >> 5) * 2048 + m * 32 + swz_p(m, kk & 31)] = f2bf(v);
                }
            }
        }

        // ---- Layer 2: relu -> H2 (kb2-3) ----
        {
            v4f acc[4];
#pragma unroll
            for (int nt = 0; nt < 4; ++nt) acc[nt] = (v4f){0.f, 0.f, 0.f, 0.f};
#pragma unroll
            for (int kb = 0; kb < 2; ++kb) {
                v8s af = *(const v8s*)(A + kb * 2048 + aoff);
#pragma unroll
                for (int nt = 0; nt < 4; ++nt) MFMA16(acc[nt], af, w2f[kb][nt]);
            }
#pragma unroll
            for (int nt = 0; nt < 4; ++nt) {
                int kk = nt * 16 + l15;
#pragma unroll
                for (int r = 0; r < 4; ++r) {
                    int m = astrip + quad * 4 + r;
                    float v = acc[nt][r] + b2v[nt];
                    v = v > 0.f ? v : 0.f;
                    A[(2 + (kk >> 5)) * 2048 + m * 32 + swz_p(m, kk & 31)] = f2bf(v);
                }
            }
        }

        // ---- Layer 3 -> out ----
        {
            v4f acc[4];
#pragma unroll
            for (int nt = 0; nt < 4; ++nt) acc[nt] = (v4f){0.f, 0.f, 0.f, 0.f};
#pragma unroll
            for (int kb = 0; kb < 2; ++kb) {
                v8s af = *(const v8s*)(A + (2 + kb) * 2048 + aoff);
#pragma unroll
                for (int nt = 0; nt < 4; ++nt) MFMA16(acc[nt], af, w3f[kb][nt]);
            }
#pragma unroll
            for (int r = 0; r < 4; ++r) {
                int node = nbase + astrip + quad * 4 + r;
                if (node < NN) {
#pragma unroll
                    for (int nt = 0; nt < 4; ++nt)
                        aggout[(size_t)node * 64 + nt * 16 + l15] = acc[nt][r] + b3v[nt];
                }
            }
        }
        __syncthreads();
    }
}

extern "C" void kernel_launch(void* const* d_in, const int* in_sizes, int n_in,
                              void* d_out, int out_size, void* d_ws, size_t ws_size,
                              hipStream_t stream) {
    const float* x   = (const float*)d_in[0];
    const float* e   = (const float*)d_in[1];
    const int*   snd = (const int*)d_in[2];
    const int*   rcv = (const int*)d_in[3];
    const float* We1 = (const float*)d_in[4];  const float* be1 = (const float*)d_in[5];
    const float* We2 = (const float*)d_in[6];  const float* be2 = (const float*)d_in[7];
    const float* We3 = (const float*)d_in[8];  const float* be3 = (const float*)d_in[9];
    const float* Wn1 = (const float*)d_in[10]; const float* bn1 = (const float*)d_in[11];
    const float* Wn2 = (const float*)d_in[12]; const float* bn2 = (const float*)d_in[13];
    const float* Wn3 = (const float*)d_in[14]; const float* bn3 = (const float*)d_in[15];
    float* out = (float*)d_out;

    // out doubles as the agg buffer; zero it.
    hipMemsetAsync(out, 0, (size_t)NN * 64 * sizeof(float), stream);

    // CSR permutation in workspace (falls back to identity if ws too small).
    const size_t need = (size_t)(2 * NN + NE) * sizeof(int);
    int* perm = nullptr;
    if (ws_size >= need) {
        int* cnt = (int*)d_ws;
        int* cur = cnt + NN;
        perm     = cur + NN;
        hipMemsetAsync(cnt, 0, (size_t)NN * sizeof(int), stream);
        count_kernel<<<(NE + 255) / 256, 256, 0, stream>>>(rcv, cnt);
        scan_kernel<<<1, 1024, 0, stream>>>(cnt, cur);
        fill_kernel<<<(NE + 255) / 256, 256, 0, stream>>>(rcv, cur, perm);
    }

    edge_kernel<<<768, 256, 49152, stream>>>(x, e, snd, rcv,
                                             We1, be1, We2, be2, We3, be3,
                                             perm, out, NE / 64);

    node_kernel<<<512, 256, 32768, stream>>>(x,
                                             Wn1, bn1, Wn2, bn2, Wn3, bn3,
                                             out, (NN + 63) / 64);
}